// Round 2
// baseline (265.553 us; speedup 1.0000x reference)
//
#include <hip/hip_runtime.h>
#include <hip/hip_bf16.h>

typedef __attribute__((ext_vector_type(8))) short bf16x8;
typedef __attribute__((ext_vector_type(4))) float f32x4;

#define GRU_B 131072
#define BM 64

static __device__ __forceinline__ ushort f2bf(float f) {
  union { float f; unsigned u; } v; v.f = f;
  unsigned r = v.u + 0x7FFFu + ((v.u >> 16) & 1u);   // RNE
  return (ushort)(r >> 16);
}
static __device__ __forceinline__ unsigned pk2(float a, float b) {
  float2 t; t.x = a; t.y = b;
  __hip_bfloat162 r = __float22bfloat162_rn(t);      // v_cvt_pk_bf16_f32
  union { __hip_bfloat162 b; unsigned u; } cv; cv.b = r;
  return cv.u;
}
static __device__ __forceinline__ float fsig(float x) {
  return __builtin_amdgcn_rcpf(1.0f + __expf(-x));
}
static __device__ __forceinline__ float ftanh(float x) {
  return 1.0f - 2.0f * __builtin_amdgcn_rcpf(1.0f + __expf(2.0f * x));
}

// Pack six 128x128 fp32 weight matrices into per-lane MFMA B-fragment order:
// chunk = ((mat*8 + cb)*4 + k0b), 1KB each; within chunk: lane*16B holds
// w[k0b*32 + (lane>>4)*8 + e][cb*16 + (lane&15)] for e=0..7, as bf16.
// A B-frag load becomes ONE coalesced global_load_dwordx4 at chunk + lane*16.
__global__ void wtrans_kernel(const float* __restrict__ wz, const float* __restrict__ uz,
                              const float* __restrict__ wr, const float* __restrict__ ur,
                              const float* __restrict__ wh, const float* __restrict__ uh,
                              ushort* __restrict__ outw) {
  int f = blockIdx.x * 256 + threadIdx.x;          // 0..98303 (coalesced write)
  int mat = f >> 14;
  int rem = f & 16383;
  int chunk = rem >> 9;                            // 0..31
  int lane = (rem >> 3) & 63;
  int e = rem & 7;
  int cb = chunk >> 2, k0b = chunk & 3;
  int n = cb * 16 + (lane & 15);
  int k = k0b * 32 + (lane >> 4) * 8 + e;
  const float* src = (mat == 0) ? wz : (mat == 1) ? uz : (mat == 2) ? wr
                   : (mat == 3) ? ur : (mat == 4) ? wh : uh;
  outw[f] = f2bf(src[k * 128 + n]);
}

__global__ __launch_bounds__(256, 4) void gru_kernel(
    const float* __restrict__ x, const float* __restrict__ hprev,
    const ushort* __restrict__ wt,
    const float* __restrict__ bz, const float* __restrict__ br,
    const float* __restrict__ bh, float* __restrict__ out) {
  __shared__ ushort rhs[BM * 128];   // r*h_prev bf16, XOR-swizzled rows (16 KB)

  const int tid = threadIdx.x;
  const int lane = tid & 63;
  const int wid = tid >> 6;          // 4 waves: column partition (32 cols each)
  const int l15 = lane & 15;
  const int q = lane >> 4;
  const long row0 = (long)blockIdx.x * BM;
  const int n0 = wid * 32;

  // A-fragment directly from global fp32 (two float4 = dense 128B row segments)
  auto ldA = [&](const float* base, int mr, int k0) -> bf16x8 {
    const float* p = base + (row0 + mr * 16 + l15) * 128 + k0 + q * 8;
    float4 lo = *(const float4*)p;
    float4 hi = *(const float4*)(p + 4);
    union { bf16x8 v; unsigned u[4]; } r;
    r.u[0] = pk2(lo.x, lo.y); r.u[1] = pk2(lo.z, lo.w);
    r.u[2] = pk2(hi.x, hi.y); r.u[3] = pk2(hi.z, hi.w);
    return r.v;
  };
  // B-fragment: one coalesced 16B/lane load from packed weights
  auto ldB = [&](int m, int nc, int k0) -> bf16x8 {
    return *(const bf16x8*)(wt + (((((m << 3) + (wid << 1) + nc) << 2) + (k0 >> 5)) << 9)
                               + (lane << 3));
  };
  // Uh A-fragment from swizzled rhs LDS
  auto ldsA = [&](int mr, int k0) -> bf16x8 {
    int row = mr * 16 + l15;
    int bo = (row * 256 + (k0 + q * 8) * 2) ^ ((row & 7) << 4);
    return *(const bf16x8*)((const char*)rhs + bo);
  };

  // ---------------- r gate: sigmoid(x@Wr + h@Ur + br); rh -> LDS ----------------
  {
    f32x4 accr[4][2];
#pragma unroll
    for (int mr = 0; mr < 4; ++mr) { accr[mr][0] = (f32x4)0.0f; accr[mr][1] = (f32x4)0.0f; }
#pragma unroll
    for (int k0 = 0; k0 < 128; k0 += 32) {
      bf16x8 b0 = ldB(2, 0, k0), b1 = ldB(2, 1, k0);
      bf16x8 c0 = ldB(3, 0, k0), c1 = ldB(3, 1, k0);
#pragma unroll
      for (int mr = 0; mr < 4; ++mr) {
        bf16x8 ax = ldA(x, mr, k0);
        bf16x8 ah = ldA(hprev, mr, k0);
        accr[mr][0] = __builtin_amdgcn_mfma_f32_16x16x32_bf16(ax, b0, accr[mr][0], 0, 0, 0);
        accr[mr][1] = __builtin_amdgcn_mfma_f32_16x16x32_bf16(ax, b1, accr[mr][1], 0, 0, 0);
        accr[mr][0] = __builtin_amdgcn_mfma_f32_16x16x32_bf16(ah, c0, accr[mr][0], 0, 0, 0);
        accr[mr][1] = __builtin_amdgcn_mfma_f32_16x16x32_bf16(ah, c1, accr[mr][1], 0, 0, 0);
      }
    }
    float bv0 = br[n0 + l15], bv1 = br[n0 + 16 + l15];
#pragma unroll
    for (int mr = 0; mr < 4; ++mr)
#pragma unroll
      for (int nc = 0; nc < 2; ++nc)
#pragma unroll
        for (int j = 0; j < 4; ++j) {
          int row = mr * 16 + q * 4 + j;
          int col = n0 + nc * 16 + l15;
          float rv = fsig(accr[mr][nc][j] + (nc ? bv1 : bv0));
          float hp = hprev[(row0 + row) * 128 + col];
          int bo = (row * 256 + col * 2) ^ ((row & 7) << 4);
          *(ushort*)((char*)rhs + bo) = f2bf(rv * hp);
        }
  }

  // ---------------- z gate: sigmoid(x@Wz + h@Uz + bz) (x,h L1/L2-hot) ----------------
  f32x4 accz[4][2];
#pragma unroll
  for (int mr = 0; mr < 4; ++mr) { accz[mr][0] = (f32x4)0.0f; accz[mr][1] = (f32x4)0.0f; }
#pragma unroll
  for (int k0 = 0; k0 < 128; k0 += 32) {
    bf16x8 b0 = ldB(0, 0, k0), b1 = ldB(0, 1, k0);
    bf16x8 c0 = ldB(1, 0, k0), c1 = ldB(1, 1, k0);
#pragma unroll
    for (int mr = 0; mr < 4; ++mr) {
      bf16x8 ax = ldA(x, mr, k0);
      bf16x8 ah = ldA(hprev, mr, k0);
      accz[mr][0] = __builtin_amdgcn_mfma_f32_16x16x32_bf16(ax, b0, accz[mr][0], 0, 0, 0);
      accz[mr][1] = __builtin_amdgcn_mfma_f32_16x16x32_bf16(ax, b1, accz[mr][1], 0, 0, 0);
      accz[mr][0] = __builtin_amdgcn_mfma_f32_16x16x32_bf16(ah, c0, accz[mr][0], 0, 0, 0);
      accz[mr][1] = __builtin_amdgcn_mfma_f32_16x16x32_bf16(ah, c1, accz[mr][1], 0, 0, 0);
    }
  }
  {
    float bv0 = bz[n0 + l15], bv1 = bz[n0 + 16 + l15];
#pragma unroll
    for (int mr = 0; mr < 4; ++mr)
#pragma unroll
      for (int j = 0; j < 4; ++j) {
        accz[mr][0][j] = fsig(accz[mr][0][j] + bv0);
        accz[mr][1][j] = fsig(accz[mr][1][j] + bv1);
      }
  }

  // ---------------- x@Wh (still pre-barrier) ----------------
  f32x4 acch[4][2];
#pragma unroll
  for (int mr = 0; mr < 4; ++mr) { acch[mr][0] = (f32x4)0.0f; acch[mr][1] = (f32x4)0.0f; }
#pragma unroll
  for (int k0 = 0; k0 < 128; k0 += 32) {
    bf16x8 b0 = ldB(4, 0, k0), b1 = ldB(4, 1, k0);
#pragma unroll
    for (int mr = 0; mr < 4; ++mr) {
      bf16x8 ax = ldA(x, mr, k0);
      acch[mr][0] = __builtin_amdgcn_mfma_f32_16x16x32_bf16(ax, b0, acch[mr][0], 0, 0, 0);
      acch[mr][1] = __builtin_amdgcn_mfma_f32_16x16x32_bf16(ax, b1, acch[mr][1], 0, 0, 0);
    }
  }

  __syncthreads();   // all waves' rh in LDS

  // ---------------- += (r*h)@Uh ----------------
#pragma unroll
  for (int k0 = 0; k0 < 128; k0 += 32) {
    bf16x8 b0 = ldB(5, 0, k0), b1 = ldB(5, 1, k0);
#pragma unroll
    for (int mr = 0; mr < 4; ++mr) {
      bf16x8 ar = ldsA(mr, k0);
      acch[mr][0] = __builtin_amdgcn_mfma_f32_16x16x32_bf16(ar, b0, acch[mr][0], 0, 0, 0);
      acch[mr][1] = __builtin_amdgcn_mfma_f32_16x16x32_bf16(ar, b1, acch[mr][1], 0, 0, 0);
    }
  }

  // ---------------- epilogue: h_t = (1-z)*h + z*tanh(acch+bh) ----------------
  {
    float bv0 = bh[n0 + l15], bv1 = bh[n0 + 16 + l15];
#pragma unroll
    for (int mr = 0; mr < 4; ++mr)
#pragma unroll
      for (int nc = 0; nc < 2; ++nc)
#pragma unroll
        for (int j = 0; j < 4; ++j) {
          int row = mr * 16 + q * 4 + j;
          int col = n0 + nc * 16 + l15;
          float hc = ftanh(acch[mr][nc][j] + (nc ? bv1 : bv0));
          float zv = accz[mr][nc][j];
          float hp = hprev[(row0 + row) * 128 + col];
          out[(row0 + row) * 128 + col] = (1.0f - zv) * hp + zv * hc;
        }
  }
}

extern "C" void kernel_launch(void* const* d_in, const int* in_sizes, int n_in,
                              void* d_out, int out_size, void* d_ws, size_t ws_size,
                              hipStream_t stream) {
  const float* x  = (const float*)d_in[0];
  const float* h  = (const float*)d_in[1];
  const float* Wz = (const float*)d_in[2];
  const float* Uz = (const float*)d_in[3];
  const float* bz = (const float*)d_in[4];
  const float* Wr = (const float*)d_in[5];
  const float* Ur = (const float*)d_in[6];
  const float* br = (const float*)d_in[7];
  const float* Wh = (const float*)d_in[8];
  const float* Uh = (const float*)d_in[9];
  const float* bh = (const float*)d_in[10];
  ushort* wt = (ushort*)d_ws;   // 98304 bf16 = 192 KB packed fragment order

  hipLaunchKernelGGL(wtrans_kernel, dim3(384), dim3(256), 0, stream,
                     Wz, Uz, Wr, Ur, Wh, Uh, wt);
  hipLaunchKernelGGL(gru_kernel, dim3(GRU_B / BM), dim3(256), 0, stream,
                     x, h, wt, bz, br, bh, (float*)d_out);
}

// Round 3
// 89.757 us; speedup vs baseline: 2.9586x; 2.9586x over previous
//
#include <hip/hip_runtime.h>
#include <hip/hip_bf16.h>

typedef __attribute__((ext_vector_type(8))) short bf16x8;
typedef __attribute__((ext_vector_type(4))) float f32x4;

#define GRU_B 131072
#define BM 32

static __device__ __forceinline__ ushort f2bf(float f) {
  union { float f; unsigned u; } v; v.f = f;
  unsigned r = v.u + 0x7FFFu + ((v.u >> 16) & 1u);   // RNE
  return (ushort)(r >> 16);
}
static __device__ __forceinline__ float bf2f(ushort u) {
  union { unsigned u; float f; } v; v.u = ((unsigned)u) << 16;
  return v.f;
}
static __device__ __forceinline__ unsigned pk2(float a, float b) {
  float2 t; t.x = a; t.y = b;
  __hip_bfloat162 r = __float22bfloat162_rn(t);      // v_cvt_pk_bf16_f32
  union { __hip_bfloat162 b; unsigned u; } cv; cv.b = r;
  return cv.u;
}
static __device__ __forceinline__ float fsig(float x) {
  return __builtin_amdgcn_rcpf(1.0f + __expf(-x));
}
static __device__ __forceinline__ float ftanh(float x) {
  return 1.0f - 2.0f * __builtin_amdgcn_rcpf(1.0f + __expf(2.0f * x));
}

// Pack six 128x128 fp32 weight matrices into per-lane MFMA B-fragment order:
// chunk = ((mat*8 + cb)*4 + k0b), 1KB each; within chunk lane*16B holds
// w[k0b*32 + (lane>>4)*8 + e][cb*16 + (lane&15)], e=0..7, bf16.
// A B-frag load is ONE coalesced global_load_dwordx4 at chunk + lane*16.
__global__ void wtrans_kernel(const float* __restrict__ wz, const float* __restrict__ uz,
                              const float* __restrict__ wr, const float* __restrict__ ur,
                              const float* __restrict__ wh, const float* __restrict__ uh,
                              ushort* __restrict__ outw) {
  int f = blockIdx.x * 256 + threadIdx.x;          // 0..98303 (coalesced write)
  int mat = f >> 14;
  int rem = f & 16383;
  int chunk = rem >> 9;                            // 0..31
  int lane = (rem >> 3) & 63;
  int e = rem & 7;
  int cb = chunk >> 2, k0b = chunk & 3;
  int n = cb * 16 + (lane & 15);
  int k = k0b * 32 + (lane >> 4) * 8 + e;
  const float* src = (mat == 0) ? wz : (mat == 1) ? uz : (mat == 2) ? wr
                   : (mat == 3) ? ur : (mat == 4) ? wh : uh;
  outw[f] = f2bf(src[k * 128 + n]);
}

__global__ __launch_bounds__(256, 6) void gru_kernel(
    const float* __restrict__ x, const float* __restrict__ hprev,
    const ushort* __restrict__ wt,
    const float* __restrict__ bz, const float* __restrict__ br,
    const float* __restrict__ bh, float* __restrict__ out) {
  // 24 KB: xs[0..8K) hs[8K..16K) rhs[16K..24K); f32 out-tile reuses [0..16K)
  __shared__ __align__(16) char smem[24576];
  ushort* xs  = (ushort*)smem;
  ushort* hs  = (ushort*)(smem + 8192);
  ushort* rhs = (ushort*)(smem + 16384);

  const int tid = threadIdx.x;
  const int lane = tid & 63;
  const int wid = tid >> 6;          // 4 waves: column partition (32 cols each)
  const int l15 = lane & 15;
  const int q = lane >> 4;
  const long row0 = (long)blockIdx.x * BM;
  const int n0 = wid * 32;

  // ---------------- stage x, h -> LDS bf16 (swizzled rows, 256 B/row) -------
  {
    const float4* xg = (const float4*)(x + row0 * 128);
    const float4* hg = (const float4*)(hprev + row0 * 128);
#pragma unroll
    for (int i = 0; i < 4; ++i) {
      int idx = i * 256 + tid;        // float4 index, 0..1023
      int r = idx >> 5;               // row 0..31
      int cb = (idx & 31) << 3;       // byte-in-row (col*2)
      int bo = (r * 256 + cb) ^ ((r & 7) << 4);
      float4 xv = xg[idx];
      float4 hv = hg[idx];
      uint2 xp, hp;
      xp.x = pk2(xv.x, xv.y); xp.y = pk2(xv.z, xv.w);
      hp.x = pk2(hv.x, hv.y); hp.y = pk2(hv.z, hv.w);
      *(uint2*)(smem + bo) = xp;
      *(uint2*)(smem + 8192 + bo) = hp;
    }
  }
  __syncthreads();

  auto ldsA = [&](const ushort* base, int mr, int k0) -> bf16x8 {
    int row = mr * 16 + l15;
    int bo = (row * 256 + (k0 + q * 8) * 2) ^ ((row & 7) << 4);
    return *(const bf16x8*)((const char*)base + bo);
  };
  // B-fragment: one coalesced 16B/lane load from packed weights (L2-hot)
  auto ldB = [&](int m, int nc, int k0) -> bf16x8 {
    return *(const bf16x8*)(wt + (((((m << 3) + (wid << 1) + nc) << 2) + (k0 >> 5)) << 9)
                               + (lane << 3));
  };

  // ---------------- z gate: sigmoid(x@Wz + h@Uz + bz) ----------------
  f32x4 accz[2][2];
#pragma unroll
  for (int mr = 0; mr < 2; ++mr) { accz[mr][0] = (f32x4)0.0f; accz[mr][1] = (f32x4)0.0f; }
#pragma unroll
  for (int k0 = 0; k0 < 128; k0 += 32) {
    bf16x8 b0 = ldB(0, 0, k0), b1 = ldB(0, 1, k0);
    bf16x8 c0 = ldB(1, 0, k0), c1 = ldB(1, 1, k0);
#pragma unroll
    for (int mr = 0; mr < 2; ++mr) {
      bf16x8 ax = ldsA(xs, mr, k0);
      bf16x8 ah = ldsA(hs, mr, k0);
      accz[mr][0] = __builtin_amdgcn_mfma_f32_16x16x32_bf16(ax, b0, accz[mr][0], 0, 0, 0);
      accz[mr][1] = __builtin_amdgcn_mfma_f32_16x16x32_bf16(ax, b1, accz[mr][1], 0, 0, 0);
      accz[mr][0] = __builtin_amdgcn_mfma_f32_16x16x32_bf16(ah, c0, accz[mr][0], 0, 0, 0);
      accz[mr][1] = __builtin_amdgcn_mfma_f32_16x16x32_bf16(ah, c1, accz[mr][1], 0, 0, 0);
    }
  }
  {
    float bv0 = bz[n0 + l15], bv1 = bz[n0 + 16 + l15];
#pragma unroll
    for (int mr = 0; mr < 2; ++mr)
#pragma unroll
      for (int j = 0; j < 4; ++j) {
        accz[mr][0][j] = fsig(accz[mr][0][j] + bv0);
        accz[mr][1][j] = fsig(accz[mr][1][j] + bv1);
      }
  }

  // ---------------- r gate: sigmoid(x@Wr + h@Ur + br); rh -> rhs ----------------
  {
    f32x4 accr[2][2];
#pragma unroll
    for (int mr = 0; mr < 2; ++mr) { accr[mr][0] = (f32x4)0.0f; accr[mr][1] = (f32x4)0.0f; }
#pragma unroll
    for (int k0 = 0; k0 < 128; k0 += 32) {
      bf16x8 b0 = ldB(2, 0, k0), b1 = ldB(2, 1, k0);
      bf16x8 c0 = ldB(3, 0, k0), c1 = ldB(3, 1, k0);
#pragma unroll
      for (int mr = 0; mr < 2; ++mr) {
        bf16x8 ax = ldsA(xs, mr, k0);
        bf16x8 ah = ldsA(hs, mr, k0);
        accr[mr][0] = __builtin_amdgcn_mfma_f32_16x16x32_bf16(ax, b0, accr[mr][0], 0, 0, 0);
        accr[mr][1] = __builtin_amdgcn_mfma_f32_16x16x32_bf16(ax, b1, accr[mr][1], 0, 0, 0);
        accr[mr][0] = __builtin_amdgcn_mfma_f32_16x16x32_bf16(ah, c0, accr[mr][0], 0, 0, 0);
        accr[mr][1] = __builtin_amdgcn_mfma_f32_16x16x32_bf16(ah, c1, accr[mr][1], 0, 0, 0);
      }
    }
    float bv0 = br[n0 + l15], bv1 = br[n0 + 16 + l15];
#pragma unroll
    for (int mr = 0; mr < 2; ++mr)
#pragma unroll
      for (int nc = 0; nc < 2; ++nc)
#pragma unroll
        for (int j = 0; j < 4; ++j) {
          int row = mr * 16 + q * 4 + j;
          int col = n0 + nc * 16 + l15;
          float rv = fsig(accr[mr][nc][j] + (nc ? bv1 : bv0));
          int bo = (row * 256 + col * 2) ^ ((row & 7) << 4);
          float hp = bf2f(*(const ushort*)((const char*)hs + bo));
          *(ushort*)((char*)rhs + bo) = f2bf(rv * hp);
        }
  }

  // ---------------- xwh = x@Wh ----------------
  f32x4 acch[2][2];
#pragma unroll
  for (int mr = 0; mr < 2; ++mr) { acch[mr][0] = (f32x4)0.0f; acch[mr][1] = (f32x4)0.0f; }
#pragma unroll
  for (int k0 = 0; k0 < 128; k0 += 32) {
    bf16x8 b0 = ldB(4, 0, k0), b1 = ldB(4, 1, k0);
#pragma unroll
    for (int mr = 0; mr < 2; ++mr) {
      bf16x8 ax = ldsA(xs, mr, k0);
      acch[mr][0] = __builtin_amdgcn_mfma_f32_16x16x32_bf16(ax, b0, acch[mr][0], 0, 0, 0);
      acch[mr][1] = __builtin_amdgcn_mfma_f32_16x16x32_bf16(ax, b1, acch[mr][1], 0, 0, 0);
    }
  }

  __syncthreads();   // all waves' rh in rhs

  // ---------------- += (r*h)@Uh ----------------
#pragma unroll
  for (int k0 = 0; k0 < 128; k0 += 32) {
    bf16x8 b0 = ldB(5, 0, k0), b1 = ldB(5, 1, k0);
#pragma unroll
    for (int mr = 0; mr < 2; ++mr) {
      bf16x8 ar = ldsA(rhs, mr, k0);
      acch[mr][0] = __builtin_amdgcn_mfma_f32_16x16x32_bf16(ar, b0, acch[mr][0], 0, 0, 0);
      acch[mr][1] = __builtin_amdgcn_mfma_f32_16x16x32_bf16(ar, b1, acch[mr][1], 0, 0, 0);
    }
  }

  // ---------------- epilogue: h_t = (1-z)*h + z*tanh(acch+bh), into regs ------
  {
    float bv0 = bh[n0 + l15], bv1 = bh[n0 + 16 + l15];
#pragma unroll
    for (int mr = 0; mr < 2; ++mr)
#pragma unroll
      for (int nc = 0; nc < 2; ++nc)
#pragma unroll
        for (int j = 0; j < 4; ++j) {
          int row = mr * 16 + q * 4 + j;
          int col = n0 + nc * 16 + l15;
          float hc = ftanh(acch[mr][nc][j] + (nc ? bv1 : bv0));
          float zv = accz[mr][nc][j];
          int bo = (row * 256 + col * 2) ^ ((row & 7) << 4);
          float hp = bf2f(*(const ushort*)((const char*)hs + bo));
          acch[mr][nc][j] = (1.0f - zv) * hp + zv * hc;
        }
  }

  __syncthreads();   // done reading hs/xs — reuse [0..16K) as f32 out-tile

  {
    float* ot = (float*)smem;   // [32][128] f32, 16B-granule XOR swizzle
#pragma unroll
    for (int mr = 0; mr < 2; ++mr)
#pragma unroll
      for (int nc = 0; nc < 2; ++nc)
#pragma unroll
        for (int j = 0; j < 4; ++j) {
          int row = mr * 16 + q * 4 + j;
          int col = n0 + nc * 16 + l15;
          int bo = (row * 512 + col * 4) ^ ((row & 7) << 4);
          *(float*)((char*)ot + bo) = acch[mr][nc][j];
        }
  }

  __syncthreads();

  // coalesced float4 stores
  {
#pragma unroll
    for (int i = 0; i < 4; ++i) {
      int idx = i * 256 + tid;        // float4 index 0..1023
      int row = idx >> 5;
      int c4 = idx & 31;
      int bo = (row * 512 + c4 * 16) ^ ((row & 7) << 4);
      float4 v = *(const float4*)(smem + bo);
      *(float4*)(out + (row0 + row) * 128 + c4 * 4) = v;
    }
  }
}

extern "C" void kernel_launch(void* const* d_in, const int* in_sizes, int n_in,
                              void* d_out, int out_size, void* d_ws, size_t ws_size,
                              hipStream_t stream) {
  const float* x  = (const float*)d_in[0];
  const float* h  = (const float*)d_in[1];
  const float* Wz = (const float*)d_in[2];
  const float* Uz = (const float*)d_in[3];
  const float* bz = (const float*)d_in[4];
  const float* Wr = (const float*)d_in[5];
  const float* Ur = (const float*)d_in[6];
  const float* br = (const float*)d_in[7];
  const float* Wh = (const float*)d_in[8];
  const float* Uh = (const float*)d_in[9];
  const float* bh = (const float*)d_in[10];
  ushort* wt = (ushort*)d_ws;   // 98304 bf16 = 192 KB packed fragment order

  hipLaunchKernelGGL(wtrans_kernel, dim3(384), dim3(256), 0, stream,
                     Wz, Uz, Wr, Ur, Wh, Uh, wt);
  hipLaunchKernelGGL(gru_kernel, dim3(GRU_B / BM), dim3(256), 0, stream,
                     x, h, wt, bz, br, bh, (float*)d_out);
}

// Round 4
// 60.236 us; speedup vs baseline: 4.4085x; 1.4901x over previous
//
#include <hip/hip_runtime.h>
#include <hip/hip_bf16.h>

typedef __attribute__((ext_vector_type(8))) short bf16x8;
typedef __attribute__((ext_vector_type(4))) float f32x4;

#define GRU_B 131072
#define BM 32

static __device__ __forceinline__ ushort f2bf(float f) {
  union { float f; unsigned u; } v; v.f = f;
  unsigned r = v.u + 0x7FFFu + ((v.u >> 16) & 1u);   // RNE
  return (ushort)(r >> 16);
}
static __device__ __forceinline__ float bf2f(ushort u) {
  union { unsigned u; float f; } v; v.u = ((unsigned)u) << 16;
  return v.f;
}
static __device__ __forceinline__ unsigned pk2(float a, float b) {
  float2 t; t.x = a; t.y = b;
  __hip_bfloat162 r = __float22bfloat162_rn(t);      // v_cvt_pk_bf16_f32
  union { __hip_bfloat162 b; unsigned u; } cv; cv.b = r;
  return cv.u;
}
static __device__ __forceinline__ float fsig(float x) {
  return __builtin_amdgcn_rcpf(1.0f + __expf(-x));
}
static __device__ __forceinline__ float ftanh(float x) {
  return 1.0f - 2.0f * __builtin_amdgcn_rcpf(1.0f + __expf(2.0f * x));
}
static __device__ __forceinline__ f32x4 splat4(float s) {
  f32x4 v = {s, s, s, s}; return v;
}

// Pack six 128x128 fp32 weight matrices into per-lane MFMA B-fragment order:
// frag = ((mat*8 + cb)*4 + kb), 1KB each; within frag lane*16B holds
// w[kb*32 + (lane>>4)*8 + e][cb*16 + (lane&15)], e=0..7, bf16.
// A B-frag load is ONE coalesced global_load_dwordx4 at frag + lane*16.
__global__ void wtrans_kernel(const float* __restrict__ wz, const float* __restrict__ uz,
                              const float* __restrict__ wr, const float* __restrict__ ur,
                              const float* __restrict__ wh, const float* __restrict__ uh,
                              ushort* __restrict__ outw) {
  int f = blockIdx.x * 256 + threadIdx.x;          // 0..98303 (coalesced write)
  int mat = f >> 14;
  int rem = f & 16383;
  int chunk = rem >> 9;                            // 0..31
  int lane = (rem >> 3) & 63;
  int e = rem & 7;
  int cb = chunk >> 2, k0b = chunk & 3;
  int n = cb * 16 + (lane & 15);
  int k = k0b * 32 + (lane >> 4) * 8 + e;
  const float* src = (mat == 0) ? wz : (mat == 1) ? uz : (mat == 2) ? wr
                   : (mat == 3) ? ur : (mat == 4) ? wh : uh;
  outw[f] = f2bf(src[k * 128 + n]);
}

#define MFMA __builtin_amdgcn_mfma_f32_16x16x32_bf16

__global__ __launch_bounds__(256, 4) void gru_kernel(
    const float* __restrict__ x, const float* __restrict__ hprev,
    const ushort* __restrict__ wt,
    const float* __restrict__ bz, const float* __restrict__ br,
    const float* __restrict__ bh, float* __restrict__ out) {
  // 24 KB: xs[0..8K) hs[8K..16K) rhs[16K..24K); f32 out-tile reuses [0..16K)
  __shared__ __align__(16) char smem[24576];
  ushort* xs  = (ushort*)smem;
  ushort* hs  = (ushort*)(smem + 8192);
  ushort* rhs = (ushort*)(smem + 16384);

  const int tid = threadIdx.x;
  const int lane = tid & 63;
  const int wid = tid >> 6;          // 4 waves: column partition (32 cols each)
  const int l15 = lane & 15;
  const int q = lane >> 4;
  const long row0 = (long)blockIdx.x * BM;
  const int n0 = wid * 32;

  // early per-lane bias loads (folded into accumulator init)
  float brv0 = br[n0 + l15], brv1 = br[n0 + 16 + l15];
  float bzv0 = bz[n0 + l15], bzv1 = bz[n0 + 16 + l15];
  float bhv0 = bh[n0 + l15], bhv1 = bh[n0 + 16 + l15];

  const ushort* wlane = wt + (lane << 3);
  auto wfrag = [&](int mat, int nc, int kb) -> const bf16x8* {
    return (const bf16x8*)(wlane + (((((mat << 3) + (wid << 1) + nc) << 2) + kb) << 9));
  };

  // hoist ALL Wr/Ur fragments — L2 latency overlaps the HBM staging latency
  bf16x8 rB[4][4];
#pragma unroll
  for (int kb = 0; kb < 4; ++kb) {
    rB[kb][0] = *wfrag(2, 0, kb); rB[kb][1] = *wfrag(2, 1, kb);
    rB[kb][2] = *wfrag(3, 0, kb); rB[kb][3] = *wfrag(3, 1, kb);
  }

  // ---------------- stage x, h -> LDS bf16 (swizzled rows, 256 B/row) -------
  {
    const float4* xg = (const float4*)(x + row0 * 128);
    const float4* hg = (const float4*)(hprev + row0 * 128);
#pragma unroll
    for (int i = 0; i < 4; ++i) {
      int idx = i * 256 + tid;        // float4 index, 0..1023
      int r = idx >> 5;               // row 0..31
      int cb = (idx & 31) << 3;       // byte-in-row (col*2)
      int bo = (r * 256 + cb) ^ ((r & 7) << 4);
      float4 xv = xg[idx];
      float4 hv = hg[idx];
      uint2 xp, hp;
      xp.x = pk2(xv.x, xv.y); xp.y = pk2(xv.z, xv.w);
      hp.x = pk2(hv.x, hv.y); hp.y = pk2(hv.z, hv.w);
      *(uint2*)(smem + bo) = xp;
      *(uint2*)(smem + 8192 + bo) = hp;
    }
  }
  __syncthreads();

  auto ldsA = [&](const ushort* base, int mr, int k0) -> bf16x8 {
    int row = mr * 16 + l15;
    int bo = (row * 256 + (k0 + q * 8) * 2) ^ ((row & 7) << 4);
    return *(const bf16x8*)((const char*)base + bo);
  };

  // ---------------- r gate first (rhs barrier ASAP): sigmoid(x@Wr+h@Ur+br) --
  f32x4 accr[2][2];
#pragma unroll
  for (int mr = 0; mr < 2; ++mr) {
    accr[mr][0] = splat4(brv0); accr[mr][1] = splat4(brv1);
  }
#pragma unroll
  for (int kb = 0; kb < 4; ++kb) {
#pragma unroll
    for (int mr = 0; mr < 2; ++mr) {
      bf16x8 ax = ldsA(xs, mr, kb * 32);
      bf16x8 ah = ldsA(hs, mr, kb * 32);
      accr[mr][0] = MFMA(ax, rB[kb][0], accr[mr][0], 0, 0, 0);
      accr[mr][1] = MFMA(ax, rB[kb][1], accr[mr][1], 0, 0, 0);
      accr[mr][0] = MFMA(ah, rB[kb][2], accr[mr][0], 0, 0, 0);
      accr[mr][1] = MFMA(ah, rB[kb][3], accr[mr][1], 0, 0, 0);
    }
  }

  // prefetch merged-pass kb=0 fragments (overlaps rh epilogue + barrier)
  bf16x8 mB[2][8];
  mB[0][0] = *wfrag(0, 0, 0); mB[0][1] = *wfrag(0, 1, 0);
  mB[0][2] = *wfrag(1, 0, 0); mB[0][3] = *wfrag(1, 1, 0);
  mB[0][4] = *wfrag(4, 0, 0); mB[0][5] = *wfrag(4, 1, 0);
  mB[0][6] = *wfrag(5, 0, 0); mB[0][7] = *wfrag(5, 1, 0);

  // rh = sigmoid(accr) * h_prev -> rhs
#pragma unroll
  for (int mr = 0; mr < 2; ++mr)
#pragma unroll
    for (int nc = 0; nc < 2; ++nc)
#pragma unroll
      for (int j = 0; j < 4; ++j) {
        int row = mr * 16 + q * 4 + j;
        int col = n0 + nc * 16 + l15;
        float rv = fsig(accr[mr][nc][j]);
        int bo = (row * 256 + col * 2) ^ ((row & 7) << 4);
        float hp = bf2f(*(const ushort*)((const char*)hs + bo));
        *(ushort*)((char*)rhs + bo) = f2bf(rv * hp);
      }

  __syncthreads();   // all waves' rh in rhs

  // ---------------- merged: z = x@Wz + h@Uz, hcand = x@Wh + rh@Uh ------------
  f32x4 accz[2][2], acch[2][2];
#pragma unroll
  for (int mr = 0; mr < 2; ++mr) {
    accz[mr][0] = splat4(bzv0); accz[mr][1] = splat4(bzv1);
    acch[mr][0] = splat4(bhv0); acch[mr][1] = splat4(bhv1);
  }
#pragma unroll
  for (int kb = 0; kb < 4; ++kb) {
    const int cur = kb & 1, nxt = cur ^ 1;
    if (kb < 3) {   // register double-buffer: issue next-kb loads early
      mB[nxt][0] = *wfrag(0, 0, kb + 1); mB[nxt][1] = *wfrag(0, 1, kb + 1);
      mB[nxt][2] = *wfrag(1, 0, kb + 1); mB[nxt][3] = *wfrag(1, 1, kb + 1);
      mB[nxt][4] = *wfrag(4, 0, kb + 1); mB[nxt][5] = *wfrag(4, 1, kb + 1);
      mB[nxt][6] = *wfrag(5, 0, kb + 1); mB[nxt][7] = *wfrag(5, 1, kb + 1);
    }
#pragma unroll
    for (int mr = 0; mr < 2; ++mr) {
      bf16x8 ax = ldsA(xs, mr, kb * 32);
      bf16x8 ah = ldsA(hs, mr, kb * 32);
      bf16x8 ar = ldsA(rhs, mr, kb * 32);
      accz[mr][0] = MFMA(ax, mB[cur][0], accz[mr][0], 0, 0, 0);
      accz[mr][1] = MFMA(ax, mB[cur][1], accz[mr][1], 0, 0, 0);
      accz[mr][0] = MFMA(ah, mB[cur][2], accz[mr][0], 0, 0, 0);
      accz[mr][1] = MFMA(ah, mB[cur][3], accz[mr][1], 0, 0, 0);
      acch[mr][0] = MFMA(ax, mB[cur][4], acch[mr][0], 0, 0, 0);
      acch[mr][1] = MFMA(ax, mB[cur][5], acch[mr][1], 0, 0, 0);
      acch[mr][0] = MFMA(ar, mB[cur][6], acch[mr][0], 0, 0, 0);
      acch[mr][1] = MFMA(ar, mB[cur][7], acch[mr][1], 0, 0, 0);
    }
  }

  // ---------------- epilogue: h_t = hp + z*(hc - hp), into acch --------------
#pragma unroll
  for (int mr = 0; mr < 2; ++mr)
#pragma unroll
    for (int nc = 0; nc < 2; ++nc)
#pragma unroll
      for (int j = 0; j < 4; ++j) {
        int row = mr * 16 + q * 4 + j;
        int col = n0 + nc * 16 + l15;
        float hc = ftanh(acch[mr][nc][j]);
        float zv = fsig(accz[mr][nc][j]);
        int bo = (row * 256 + col * 2) ^ ((row & 7) << 4);
        float hp = bf2f(*(const ushort*)((const char*)hs + bo));
        acch[mr][nc][j] = hp + zv * (hc - hp);
      }

  __syncthreads();   // done reading hs/xs — reuse [0..16K) as f32 out-tile

  {
    float* ot = (float*)smem;   // [32][128] f32, 16B-granule XOR swizzle
#pragma unroll
    for (int mr = 0; mr < 2; ++mr)
#pragma unroll
      for (int nc = 0; nc < 2; ++nc)
#pragma unroll
        for (int j = 0; j < 4; ++j) {
          int row = mr * 16 + q * 4 + j;
          int col = n0 + nc * 16 + l15;
          int bo = (row * 512 + col * 4) ^ ((row & 7) << 4);
          *(float*)((char*)ot + bo) = acch[mr][nc][j];
        }
  }

  __syncthreads();

  // coalesced float4 stores
  {
#pragma unroll
    for (int i = 0; i < 4; ++i) {
      int idx = i * 256 + tid;        // float4 index 0..1023
      int row = idx >> 5;
      int c4 = idx & 31;
      int bo = (row * 512 + c4 * 16) ^ ((row & 7) << 4);
      float4 v = *(const float4*)(smem + bo);
      *(float4*)(out + (row0 + row) * 128 + c4 * 4) = v;
    }
  }
}

extern "C" void kernel_launch(void* const* d_in, const int* in_sizes, int n_in,
                              void* d_out, int out_size, void* d_ws, size_t ws_size,
                              hipStream_t stream) {
  const float* x  = (const float*)d_in[0];
  const float* h  = (const float*)d_in[1];
  const float* Wz = (const float*)d_in[2];
  const float* Uz = (const float*)d_in[3];
  const float* bz = (const float*)d_in[4];
  const float* Wr = (const float*)d_in[5];
  const float* Ur = (const float*)d_in[6];
  const float* br = (const float*)d_in[7];
  const float* Wh = (const float*)d_in[8];
  const float* Uh = (const float*)d_in[9];
  const float* bh = (const float*)d_in[10];
  ushort* wt = (ushort*)d_ws;   // 98304 bf16 = 192 KB packed fragment order

  hipLaunchKernelGGL(wtrans_kernel, dim3(384), dim3(256), 0, stream,
                     Wz, Uz, Wr, Ur, Wh, Uh, wt);
  hipLaunchKernelGGL(gru_kernel, dim3(GRU_B / BM), dim3(256), 0, stream,
                     x, h, wt, bz, br, bh, (float*)d_out);
}